// Round 5
// baseline (1296.944 us; speedup 1.0000x reference)
//
#include <hip/hip_runtime.h>

#define PP 2048     // P (pred rows)
#define SSEQ 2048   // S (key rows)
#define DDIM 1024   // D
#define NH 16       // heads
#define DH 64       // head dim

typedef __attribute__((ext_vector_type(4))) float f32x4;
typedef __attribute__((ext_vector_type(8))) short bf16x8;
typedef __attribute__((ext_vector_type(4))) short bf16x4;

__device__ __forceinline__ short f2bf(float f) {
  unsigned u = __builtin_bit_cast(unsigned, f);
  u += 0x7FFFu + ((u >> 16) & 1u);   // RNE
  return (short)(u >> 16);
}
__device__ __forceinline__ float bf2f(unsigned short u) {
  return __builtin_bit_cast(float, ((unsigned)u) << 16);
}

// ---------------- GEMM: Y[2048][1024] = X @ W^T + bias ----------------
template<int XMODE, int YF32>
__device__ __forceinline__ void gemm_body(const void* __restrict__ Xv,
                                          const void* __restrict__ X2,
                                          const float* __restrict__ W,
                                          const float* __restrict__ bias,
                                          void* __restrict__ Yv) {
  __shared__ short As[64][40];
  __shared__ short Bs[128][40];
  const int tid = threadIdx.x, lane = tid & 63, wid = tid >> 6;
  const int wm = (wid >> 1) * 32, wn = (wid & 1) * 64;
  const int m0 = blockIdx.y * 64, n0 = blockIdx.x * 128;
  const int g = lane >> 4, ln = lane & 15;
  f32x4 acc[2][4] = {};
  for (int k0 = 0; k0 < DDIM; k0 += 32) {
    __syncthreads();
#pragma unroll
    for (int pass = 0; pass < 2; ++pass) {
      const int e = pass * 1024 + tid * 4;
      const int r = e >> 5, c = e & 31;
      if (XMODE == 0) {
        const float* X = (const float*)Xv;
        float4 x = *(const float4*)(X + (size_t)(m0 + r) * DDIM + k0 + c);
        bf16x4 xb; xb[0] = f2bf(x.x); xb[1] = f2bf(x.y); xb[2] = f2bf(x.z); xb[3] = f2bf(x.w);
        *(bf16x4*)&As[r][c] = xb;
      } else {
        const unsigned short* A0 = (const unsigned short*)Xv;
        const unsigned short* A1 = (const unsigned short*)X2;
        bf16x4 a0 = *(const bf16x4*)(A0 + (size_t)(m0 + r) * DDIM + k0 + c);
        bf16x4 a1 = *(const bf16x4*)(A1 + (size_t)(m0 + r) * DDIM + k0 + c);
        bf16x4 s;
#pragma unroll
        for (int u = 0; u < 4; ++u)
          s[u] = f2bf(bf2f((unsigned short)a0[u]) + bf2f((unsigned short)a1[u]));
        *(bf16x4*)&As[r][c] = s;
      }
    }
#pragma unroll
    for (int pass = 0; pass < 4; ++pass) {
      const int e = pass * 1024 + tid * 4;
      const int r = e >> 5, c = e & 31;
      float4 w = *(const float4*)(W + (size_t)(n0 + r) * DDIM + k0 + c);
      bf16x4 wb; wb[0] = f2bf(w.x); wb[1] = f2bf(w.y); wb[2] = f2bf(w.z); wb[3] = f2bf(w.w);
      *(bf16x4*)&Bs[r][c] = wb;
    }
    __syncthreads();
    bf16x8 a[2], b[4];
#pragma unroll
    for (int mi = 0; mi < 2; ++mi) a[mi] = *(const bf16x8*)&As[wm + mi * 16 + ln][g * 8];
#pragma unroll
    for (int ni = 0; ni < 4; ++ni) b[ni] = *(const bf16x8*)&Bs[wn + ni * 16 + ln][g * 8];
#pragma unroll
    for (int mi = 0; mi < 2; ++mi)
#pragma unroll
      for (int ni = 0; ni < 4; ++ni)
        acc[mi][ni] = __builtin_amdgcn_mfma_f32_16x16x32_bf16(a[mi], b[ni], acc[mi][ni], 0, 0, 0);
  }
#pragma unroll
  for (int mi = 0; mi < 2; ++mi)
#pragma unroll
    for (int ni = 0; ni < 4; ++ni)
#pragma unroll
      for (int r = 0; r < 4; ++r) {
        const int m = m0 + wm + mi * 16 + g * 4 + r;
        const int n = n0 + wn + ni * 16 + ln;
        const float v = acc[mi][ni][r] + bias[n];
        if (YF32) ((float*)Yv)[(size_t)m * DDIM + n] = v;
        else ((unsigned short*)Yv)[(size_t)m * DDIM + n] = (unsigned short)f2bf(v);
      }
}

__global__ __launch_bounds__(256, 4) void qkv_proj(
    const float* __restrict__ Q, const float* __restrict__ Kin, const float* __restrict__ V,
    const float* __restrict__ Wq, const float* __restrict__ Wk, const float* __restrict__ Wv,
    const float* __restrict__ bq, const float* __restrict__ bk, const float* __restrict__ bv,
    unsigned short* __restrict__ qb, unsigned short* __restrict__ kb, unsigned short* __restrict__ vb) {
  const int z = blockIdx.z;
  const float* X = (z == 0) ? Q : (z == 1) ? Kin : V;
  const float* W = (z == 0) ? Wq : (z == 1) ? Wk : Wv;
  const float* b = (z == 0) ? bq : (z == 1) ? bk : bv;
  unsigned short* Y = (z == 0) ? qb : (z == 1) ? kb : vb;
  gemm_body<0, 0>(X, nullptr, W, b, Y);
}

__global__ __launch_bounds__(256, 4) void out_proj(
    const unsigned short* __restrict__ ctxp0, const unsigned short* __restrict__ ctxp1,
    const float* __restrict__ Wo, const float* __restrict__ bo, float* __restrict__ out) {
  gemm_body<2, 1>(ctxp0, ctxp1, Wo, bo, out);
}

// ---------------- V transpose: vT[d][s] = vb[s][d] ----------------
__global__ __launch_bounds__(256) void transpose_v(
    const unsigned short* __restrict__ vb, unsigned short* __restrict__ vT) {
  __shared__ unsigned short t[64][72];
  const int tid = threadIdx.x;
  const int sb = blockIdx.x * 64, db = blockIdx.y * 64;
#pragma unroll
  for (int pass = 0; pass < 2; ++pass) {
    const int e = pass * 2048 + tid * 8;
    const int r = e >> 6, c = e & 63;
    *(bf16x8*)&t[r][c] = *(const bf16x8*)(vb + (size_t)(sb + r) * DDIM + db + c);
  }
  __syncthreads();
#pragma unroll
  for (int pass = 0; pass < 2; ++pass) {
    const int e = pass * 2048 + tid * 8;
    const int r = e >> 6, c = e & 63;   // r: d row, c: s col
    bf16x8 ov;
#pragma unroll
    for (int u = 0; u < 8; ++u) ov[u] = (short)t[c + u][r];
    *(bf16x8*)(vT + (size_t)(db + r) * SSEQ + sb + c) = ov;
  }
}

// ---------------- scores v3: BARRIER-FREE (identical to R3) ----------------
__global__ __launch_bounds__(256, 3) void scores_kernel(
    const unsigned short* __restrict__ qb, const unsigned short* __restrict__ kb,
    const float* __restrict__ prev, const float* __restrict__ ch_gate,
    float* __restrict__ raw, float* __restrict__ m_part, float* __restrict__ l_part) {
  __shared__ float Rs[4][32][68];   // [wave][col-in-strip][row(+pad)]
  const int tid = threadIdx.x, lane = tid & 63, w = tid >> 6;
  const int pt = blockIdx.x, sg = blockIdx.y, h = blockIdx.z;
  const int p0 = pt * 64;
  const int g = lane >> 4, ln = lane & 15;
  const int b8 = lane & 7, c8 = lane >> 3;

  bf16x8 aq[4][2];
#pragma unroll
  for (int mi = 0; mi < 4; ++mi)
#pragma unroll
    for (int ks = 0; ks < 2; ++ks)
      aq[mi][ks] = *(const bf16x8*)(qb + (size_t)(p0 + mi * 16 + ln) * DDIM + h * DH + ks * 32 + g * 8);

  const int pc = p0 >> 8;
  float mrun[8], lrun[8];
#pragma unroll
  for (int i = 0; i < 8; ++i) { mrun[i] = -1e30f; lrun[i] = 0.f; }

  for (int t = 0; t < 4; ++t) {
    const int s0 = sg * 512 + t * 128;
    const int sw = s0 + w * 32;
    const float gate = (ch_gate[pc * 8 + (s0 >> 8)] >= 0.f) ? 1.f : 0.f;
    float4 pv[8];
#pragma unroll
    for (int it = 0; it < 8; ++it)
      pv[it] = *(const float4*)(prev + ((size_t)(p0 + 8 * it + c8) * NH + h) * SSEQ + sw + b8 * 4);
    bf16x8 bk_[2][2];
#pragma unroll
    for (int nj = 0; nj < 2; ++nj)
#pragma unroll
      for (int ks = 0; ks < 2; ++ks)
        bk_[nj][ks] = *(const bf16x8*)(kb + (size_t)(sw + nj * 16 + ln) * DDIM + h * DH + ks * 32 + g * 8);
    f32x4 acc[4][2] = {};
#pragma unroll
    for (int ks = 0; ks < 2; ++ks)
#pragma unroll
      for (int mi = 0; mi < 4; ++mi)
#pragma unroll
        for (int nj = 0; nj < 2; ++nj)
          acc[mi][nj] = __builtin_amdgcn_mfma_f32_16x16x32_bf16(aq[mi][ks], bk_[nj][ks], acc[mi][nj], 0, 0, 0);
#pragma unroll
    for (int mi = 0; mi < 4; ++mi)
#pragma unroll
      for (int nj = 0; nj < 2; ++nj)
        *(f32x4*)&Rs[w][nj * 16 + ln][mi * 16 + g * 4] = acc[mi][nj];
#pragma unroll
    for (int it = 0; it < 8; ++it) {
      const int row = 8 * it + c8;
      const int p = p0 + row;
      const int sq = sw + b8 * 4;
      float4 v;
      v.x = fmaf(Rs[w][b8 * 4 + 0][row], 0.125f, pv[it].x) * gate;
      v.y = fmaf(Rs[w][b8 * 4 + 1][row], 0.125f, pv[it].y) * gate;
      v.z = fmaf(Rs[w][b8 * 4 + 2][row], 0.125f, pv[it].z) * gate;
      v.w = fmaf(Rs[w][b8 * 4 + 3][row], 0.125f, pv[it].w) * gate;
      *(float4*)(raw + ((size_t)p * NH + h) * SSEQ + sq) = v;
      if (sq <= p) {
        const float v0 = v.x;
        const float v1 = (sq + 1 <= p) ? v.y : -1e30f;
        const float v2 = (sq + 2 <= p) ? v.z : -1e30f;
        const float v3 = (sq + 3 <= p) ? v.w : -1e30f;
        const float qm = fmaxf(fmaxf(v0, v1), fmaxf(v2, v3));
        const float mn = fmaxf(mrun[it], qm);
        lrun[it] = lrun[it] * __expf(mrun[it] - mn)
                 + __expf(v0 - mn) + __expf(v1 - mn) + __expf(v2 - mn) + __expf(v3 - mn);
        mrun[it] = mn;
      }
    }
  }
#pragma unroll
  for (int it = 0; it < 8; ++it) {
    float m = mrun[it], l = lrun[it];
#pragma unroll
    for (int mask = 1; mask < 8; mask <<= 1) {
      const float mo = __shfl_xor(m, mask);
      const float lo = __shfl_xor(l, mask);
      const float mn = fmaxf(m, mo);
      l = l * __expf(m - mn) + lo * __expf(mo - mn);
      m = mn;
    }
    if (b8 == 0) {
      const int p = p0 + 8 * it + c8;
      const size_t idx = ((size_t)(sg * 4 + w) * NH + h) * PP + p;
      m_part[idx] = m;
      l_part[idx] = l;
    }
  }
}

// ---------------- attnpv v3 (identical to R3) ----------------
__global__ __launch_bounds__(256, 4) void attnpv_kernel(
    const float* __restrict__ raw, const unsigned short* __restrict__ vT,
    const float* __restrict__ m_part, const float* __restrict__ l_part,
    float* __restrict__ attn, unsigned short* __restrict__ ctxp) {
  const int tid = threadIdx.x, lane = tid & 63, w = tid >> 6;
  const int pt = blockIdx.x, ss = blockIdx.y, h = blockIdx.z;
  const int p0 = pt * 64, wr = w * 16;
  const int g = lane >> 4, ln = lane & 15;
  const int myp = p0 + wr + ln;

  float m = -1e30f, l = 0.f;
#pragma unroll
  for (int sgw = 0; sgw < 16; ++sgw) {
    const size_t idx = ((size_t)sgw * NH + h) * PP + myp;
    const float mo = m_part[idx];
    const float lo = l_part[idx];
    const float mn = fmaxf(m, mo);
    l = l * __expf(m - mn) + lo * __expf(mo - mn);
    m = mn;
  }
  const float mm = m;
  const float il = 1.f / l;

  unsigned short* ctx = ctxp + (size_t)ss * PP * DDIM;
  f32x4 acc[4] = {};
  for (int st = 0; st < 8; ++st) {
    const int s0 = ss * 1024 + st * 128;
    if (s0 > p0 + 63) {
      const float4 z = {0.f, 0.f, 0.f, 0.f};
#pragma unroll
      for (int i = 0; i < 8; ++i) {
        const int e = i * 1024 + lane * 16;
        const int row = e >> 9, colf = (e & 511) >> 2;
        *(float4*)(attn + ((size_t)(p0 + wr + row) * NH + h) * SSEQ + s0 + colf) = z;
      }
      continue;
    }
    const size_t rbase = ((size_t)myp * NH + h) * SSEQ + s0;
    bf16x8 pa[4];
#pragma unroll
    for (int ks = 0; ks < 4; ++ks) {
      const int c0 = ks * 32 + g * 8;
      const float4 r0 = *(const float4*)(raw + rbase + c0);
      const float4 r1 = *(const float4*)(raw + rbase + c0 + 4);
      const int sb = s0 + c0;
      float4 a0, a1;
      a0.x = (sb + 0 <= myp) ? __expf(r0.x - mm) * il : 0.f;
      a0.y = (sb + 1 <= myp) ? __expf(r0.y - mm) * il : 0.f;
      a0.z = (sb + 2 <= myp) ? __expf(r0.z - mm) * il : 0.f;
      a0.w = (sb + 3 <= myp) ? __expf(r0.w - mm) * il : 0.f;
      a1.x = (sb + 4 <= myp) ? __expf(r1.x - mm) * il : 0.f;
      a1.y = (sb + 5 <= myp) ? __expf(r1.y - mm) * il : 0.f;
      a1.z = (sb + 6 <= myp) ? __expf(r1.z - mm) * il : 0.f;
      a1.w = (sb + 7 <= myp) ? __expf(r1.w - mm) * il : 0.f;
      *(float4*)(attn + rbase + c0) = a0;
      *(float4*)(attn + rbase + c0 + 4) = a1;
      bf16x8 pk;
      pk[0] = f2bf(a0.x); pk[1] = f2bf(a0.y); pk[2] = f2bf(a0.z); pk[3] = f2bf(a0.w);
      pk[4] = f2bf(a1.x); pk[5] = f2bf(a1.y); pk[6] = f2bf(a1.z); pk[7] = f2bf(a1.w);
      pa[ks] = pk;
    }
#pragma unroll
    for (int nj = 0; nj < 4; ++nj) {
#pragma unroll
      for (int ks = 0; ks < 4; ++ks) {
        const bf16x8 bv = *(const bf16x8*)(vT + (size_t)(h * DH + nj * 16 + ln) * SSEQ + s0 + ks * 32 + g * 8);
        acc[nj] = __builtin_amdgcn_mfma_f32_16x16x32_bf16(pa[ks], bv, acc[nj], 0, 0, 0);
      }
    }
  }
#pragma unroll
  for (int nj = 0; nj < 4; ++nj)
#pragma unroll
    for (int r = 0; r < 4; ++r) {
      const int p = p0 + wr + g * 4 + r;
      ctx[(size_t)p * DDIM + h * DH + nj * 16 + ln] = (unsigned short)f2bf(acc[nj][r]);
    }
}

extern "C" void kernel_launch(void* const* d_in, const int* in_sizes, int n_in,
                              void* d_out, int out_size, void* d_ws, size_t ws_size,
                              hipStream_t stream) {
  (void)in_sizes; (void)n_in; (void)out_size; (void)ws_size;
  const float* Q    = (const float*)d_in[0];
  const float* K    = (const float*)d_in[1];
  const float* V    = (const float*)d_in[2];
  const float* prev = (const float*)d_in[3];
  const float* Wq   = (const float*)d_in[4];
  const float* bq   = (const float*)d_in[5];
  const float* Wk   = (const float*)d_in[6];
  const float* bk   = (const float*)d_in[7];
  const float* Wv   = (const float*)d_in[8];
  const float* bv   = (const float*)d_in[9];
  const float* Wo   = (const float*)d_in[10];
  const float* bo   = (const float*)d_in[11];
  const float* ch_gate = (const float*)d_in[12];

  float* out  = (float*)d_out;                       // (2048,1024)
  float* attn = out + (size_t)PP * DDIM;             // (2048,16,2048)
  float* raw  = attn + (size_t)PP * NH * SSEQ;       // (2048,16,2048)

  unsigned short* qb    = (unsigned short*)d_ws;
  unsigned short* kb    = qb + (size_t)PP * DDIM;
  unsigned short* vb    = kb + (size_t)PP * DDIM;
  unsigned short* vT    = vb + (size_t)PP * DDIM;
  unsigned short* ctxp  = vT + (size_t)DDIM * SSEQ;
  float* m_part = (float*)(ctxp + (size_t)2 * PP * DDIM);
  float* l_part = m_part + (size_t)16 * NH * PP;

  dim3 blk(256);
  qkv_proj<<<dim3(DDIM / 128, PP / 64, 3), blk, 0, stream>>>(
      Q, K, V, Wq, Wk, Wv, bq, bk, bv, qb, kb, vb);
  transpose_v<<<dim3(SSEQ / 64, DDIM / 64), blk, 0, stream>>>(vb, vT);
  scores_kernel<<<dim3(PP / 64, 4, NH), blk, 0, stream>>>(
      qb, kb, prev, ch_gate, raw, m_part, l_part);
  // DIAGNOSTIC: launch attnpv 5x (idempotent — deterministic same-output).
  // attnpv_us = (dur_total - 527) / 4 relative to R3 baseline.
  for (int rep = 0; rep < 5; ++rep)
    attnpv_kernel<<<dim3(PP / 64, 2, NH), blk, 0, stream>>>(
        raw, vT, m_part, l_part, attn, ctxp);
  out_proj<<<dim3(DDIM / 128, PP / 64), blk, 0, stream>>>(
      ctxp, ctxp + (size_t)PP * DDIM, Wo, bo, out);
}

// Round 6
// 460.690 us; speedup vs baseline: 2.8152x; 2.8152x over previous
//
#include <hip/hip_runtime.h>

#define PP 2048     // P (pred rows)
#define SSEQ 2048   // S (key rows)
#define DDIM 1024   // D
#define NH 16       // heads
#define DH 64       // head dim

typedef __attribute__((ext_vector_type(4))) float f32x4;
typedef __attribute__((ext_vector_type(8))) short bf16x8;
typedef __attribute__((ext_vector_type(4))) short bf16x4;

__device__ __forceinline__ short f2bf(float f) {
  unsigned u = __builtin_bit_cast(unsigned, f);
  u += 0x7FFFu + ((u >> 16) & 1u);   // RNE
  return (short)(u >> 16);
}
__device__ __forceinline__ float bf2f(unsigned short u) {
  return __builtin_bit_cast(float, ((unsigned)u) << 16);
}

// ---------------- GEMM: Y[2048][1024] = X @ W^T + bias ----------------
// 64x128 tile, BK=64 (half the barriers of BK=32), 4 waves (2x2), wave 32x64.
template<int XMODE, int YF32>
__device__ __forceinline__ void gemm_body(const void* __restrict__ Xv,
                                          const void* __restrict__ X2,
                                          const float* __restrict__ W,
                                          const float* __restrict__ bias,
                                          void* __restrict__ Yv) {
  __shared__ short As[64][72];
  __shared__ short Bs[128][72];
  const int tid = threadIdx.x, lane = tid & 63, wid = tid >> 6;
  const int wm = (wid >> 1) * 32, wn = (wid & 1) * 64;
  const int m0 = blockIdx.y * 64, n0 = blockIdx.x * 128;
  const int g = lane >> 4, ln = lane & 15;
  f32x4 acc[2][4] = {};
  for (int k0 = 0; k0 < DDIM; k0 += 64) {
    __syncthreads();
#pragma unroll
    for (int pass = 0; pass < 4; ++pass) {   // A: 64x64
      const int e = pass * 1024 + tid * 4;
      const int r = e >> 6, c = e & 63;
      if (XMODE == 0) {
        const float* X = (const float*)Xv;
        float4 x = *(const float4*)(X + (size_t)(m0 + r) * DDIM + k0 + c);
        bf16x4 xb; xb[0] = f2bf(x.x); xb[1] = f2bf(x.y); xb[2] = f2bf(x.z); xb[3] = f2bf(x.w);
        *(bf16x4*)&As[r][c] = xb;
      } else {
        const unsigned short* A0 = (const unsigned short*)Xv;
        const unsigned short* A1 = (const unsigned short*)X2;
        bf16x4 a0 = *(const bf16x4*)(A0 + (size_t)(m0 + r) * DDIM + k0 + c);
        bf16x4 a1 = *(const bf16x4*)(A1 + (size_t)(m0 + r) * DDIM + k0 + c);
        bf16x4 s;
#pragma unroll
        for (int u = 0; u < 4; ++u)
          s[u] = f2bf(bf2f((unsigned short)a0[u]) + bf2f((unsigned short)a1[u]));
        *(bf16x4*)&As[r][c] = s;
      }
    }
#pragma unroll
    for (int pass = 0; pass < 8; ++pass) {   // B: 128x64
      const int e = pass * 1024 + tid * 4;
      const int r = e >> 6, c = e & 63;
      float4 w = *(const float4*)(W + (size_t)(n0 + r) * DDIM + k0 + c);
      bf16x4 wb; wb[0] = f2bf(w.x); wb[1] = f2bf(w.y); wb[2] = f2bf(w.z); wb[3] = f2bf(w.w);
      *(bf16x4*)&Bs[r][c] = wb;
    }
    __syncthreads();
#pragma unroll
    for (int ks = 0; ks < 2; ++ks) {
      bf16x8 a[2], b[4];
#pragma unroll
      for (int mi = 0; mi < 2; ++mi) a[mi] = *(const bf16x8*)&As[wm + mi * 16 + ln][ks * 32 + g * 8];
#pragma unroll
      for (int ni = 0; ni < 4; ++ni) b[ni] = *(const bf16x8*)&Bs[wn + ni * 16 + ln][ks * 32 + g * 8];
#pragma unroll
      for (int mi = 0; mi < 2; ++mi)
#pragma unroll
        for (int ni = 0; ni < 4; ++ni)
          acc[mi][ni] = __builtin_amdgcn_mfma_f32_16x16x32_bf16(a[mi], b[ni], acc[mi][ni], 0, 0, 0);
    }
  }
#pragma unroll
  for (int mi = 0; mi < 2; ++mi)
#pragma unroll
    for (int ni = 0; ni < 4; ++ni)
#pragma unroll
      for (int r = 0; r < 4; ++r) {
        const int m = m0 + wm + mi * 16 + g * 4 + r;
        const int n = n0 + wn + ni * 16 + ln;
        const float v = acc[mi][ni][r] + bias[n];
        if (YF32) ((float*)Yv)[(size_t)m * DDIM + n] = v;
        else ((unsigned short*)Yv)[(size_t)m * DDIM + n] = (unsigned short)f2bf(v);
      }
}

__global__ __launch_bounds__(256, 4) void qkv_proj(
    const float* __restrict__ Q, const float* __restrict__ Kin, const float* __restrict__ V,
    const float* __restrict__ Wq, const float* __restrict__ Wk, const float* __restrict__ Wv,
    const float* __restrict__ bq, const float* __restrict__ bk, const float* __restrict__ bv,
    unsigned short* __restrict__ qb, unsigned short* __restrict__ kb, unsigned short* __restrict__ vb) {
  const int z = blockIdx.z;
  const float* X = (z == 0) ? Q : (z == 1) ? Kin : V;
  const float* W = (z == 0) ? Wq : (z == 1) ? Wk : Wv;
  const float* b = (z == 0) ? bq : (z == 1) ? bk : bv;
  unsigned short* Y = (z == 0) ? qb : (z == 1) ? kb : vb;
  gemm_body<0, 0>(X, nullptr, W, b, Y);
}

__global__ __launch_bounds__(256, 4) void out_proj(
    const unsigned short* __restrict__ ctxp0, const unsigned short* __restrict__ ctxp1,
    const float* __restrict__ Wo, const float* __restrict__ bo, float* __restrict__ out) {
  gemm_body<2, 1>(ctxp0, ctxp1, Wo, bo, out);
}

// ---------------- V transpose: vT[d][s] = vb[s][d] ----------------
__global__ __launch_bounds__(256) void transpose_v(
    const unsigned short* __restrict__ vb, unsigned short* __restrict__ vT) {
  __shared__ unsigned short t[64][72];
  const int tid = threadIdx.x;
  const int sb = blockIdx.x * 64, db = blockIdx.y * 64;
#pragma unroll
  for (int pass = 0; pass < 2; ++pass) {
    const int e = pass * 2048 + tid * 8;
    const int r = e >> 6, c = e & 63;
    *(bf16x8*)&t[r][c] = *(const bf16x8*)(vb + (size_t)(sb + r) * DDIM + db + c);
  }
  __syncthreads();
#pragma unroll
  for (int pass = 0; pass < 2; ++pass) {
    const int e = pass * 2048 + tid * 8;
    const int r = e >> 6, c = e & 63;   // r: d row, c: s col
    bf16x8 ov;
#pragma unroll
    for (int u = 0; u < 8; ++u) ov[u] = (short)t[c + u][r];
    *(bf16x8*)(vT + (size_t)(db + r) * SSEQ + sb + c) = ov;
  }
}

// ---------------- scores v4: barrier-free + prev double-buffer ----------------
// grid: (P/64, 4, NH); block 256 = 4 waves, each owns a 32-col strip/tile.
__global__ __launch_bounds__(256, 3) void scores_kernel(
    const unsigned short* __restrict__ qb, const unsigned short* __restrict__ kb,
    const float* __restrict__ prev, const float* __restrict__ ch_gate,
    float* __restrict__ raw, float* __restrict__ m_part, float* __restrict__ l_part) {
  __shared__ float Rs[4][32][68];   // [wave][col-in-strip][row(+pad)]
  const int tid = threadIdx.x, lane = tid & 63, w = tid >> 6;
  const int pt = blockIdx.x, sg = blockIdx.y, h = blockIdx.z;
  const int p0 = pt * 64;
  const int g = lane >> 4, ln = lane & 15;
  const int b8 = lane & 7, c8 = lane >> 3;

  bf16x8 aq[4][2];
#pragma unroll
  for (int mi = 0; mi < 4; ++mi)
#pragma unroll
    for (int ks = 0; ks < 2; ++ks)
      aq[mi][ks] = *(const bf16x8*)(qb + (size_t)(p0 + mi * 16 + ln) * DDIM + h * DH + ks * 32 + g * 8);

  const int pc = p0 >> 8;
  float mrun[8], lrun[8];
#pragma unroll
  for (int i = 0; i < 8; ++i) { mrun[i] = -1e30f; lrun[i] = 0.f; }

  // prefetch prev for t=0
  f32x4 pv[8];
  {
    const int sw0 = sg * 512 + w * 32;
#pragma unroll
    for (int it = 0; it < 8; ++it)
      pv[it] = __builtin_nontemporal_load(
          (const f32x4*)(prev + ((size_t)(p0 + 8 * it + c8) * NH + h) * SSEQ + sw0 + b8 * 4));
  }

#pragma unroll
  for (int t = 0; t < 4; ++t) {
    const int s0 = sg * 512 + t * 128;
    const int sw = s0 + w * 32;
    const float gate = (ch_gate[pc * 8 + (s0 >> 8)] >= 0.f) ? 1.f : 0.f;
    // K fragments for this strip (L2-resident)
    bf16x8 bk_[2][2];
#pragma unroll
    for (int nj = 0; nj < 2; ++nj)
#pragma unroll
      for (int ks = 0; ks < 2; ++ks)
        bk_[nj][ks] = *(const bf16x8*)(kb + (size_t)(sw + nj * 16 + ln) * DDIM + h * DH + ks * 32 + g * 8);
    // prefetch prev for t+1 (hides HBM latency under MFMA+epilogue)
    f32x4 pvn[8];
    if (t < 3) {
      const int swn = sw + 128;
#pragma unroll
      for (int it = 0; it < 8; ++it)
        pvn[it] = __builtin_nontemporal_load(
            (const f32x4*)(prev + ((size_t)(p0 + 8 * it + c8) * NH + h) * SSEQ + swn + b8 * 4));
    }
    f32x4 acc[4][2] = {};
#pragma unroll
    for (int ks = 0; ks < 2; ++ks)
#pragma unroll
      for (int mi = 0; mi < 4; ++mi)
#pragma unroll
        for (int nj = 0; nj < 2; ++nj)
          acc[mi][nj] = __builtin_amdgcn_mfma_f32_16x16x32_bf16(aq[mi][ks], bk_[nj][ks], acc[mi][nj], 0, 0, 0);
#pragma unroll
    for (int mi = 0; mi < 4; ++mi)
#pragma unroll
      for (int nj = 0; nj < 2; ++nj)
        *(f32x4*)&Rs[w][nj * 16 + ln][mi * 16 + g * 4] = acc[mi][nj];
#pragma unroll
    for (int it = 0; it < 8; ++it) {
      const int row = 8 * it + c8;
      const int p = p0 + row;
      const int sq = sw + b8 * 4;
      f32x4 v;
      v[0] = fmaf(Rs[w][b8 * 4 + 0][row], 0.125f, pv[it][0]) * gate;
      v[1] = fmaf(Rs[w][b8 * 4 + 1][row], 0.125f, pv[it][1]) * gate;
      v[2] = fmaf(Rs[w][b8 * 4 + 2][row], 0.125f, pv[it][2]) * gate;
      v[3] = fmaf(Rs[w][b8 * 4 + 3][row], 0.125f, pv[it][3]) * gate;
      __builtin_nontemporal_store(v, (f32x4*)(raw + ((size_t)p * NH + h) * SSEQ + sq));
      if (sq <= p) {
        const float v0 = v[0];
        const float v1 = (sq + 1 <= p) ? v[1] : -1e30f;
        const float v2 = (sq + 2 <= p) ? v[2] : -1e30f;
        const float v3 = (sq + 3 <= p) ? v[3] : -1e30f;
        const float qm = fmaxf(fmaxf(v0, v1), fmaxf(v2, v3));
        const float mn = fmaxf(mrun[it], qm);
        lrun[it] = lrun[it] * __expf(mrun[it] - mn)
                 + __expf(v0 - mn) + __expf(v1 - mn) + __expf(v2 - mn) + __expf(v3 - mn);
        mrun[it] = mn;
      }
    }
    if (t < 3) {
#pragma unroll
      for (int it = 0; it < 8; ++it) pv[it] = pvn[it];
    }
  }
#pragma unroll
  for (int it = 0; it < 8; ++it) {
    float m = mrun[it], l = lrun[it];
#pragma unroll
    for (int mask = 1; mask < 8; mask <<= 1) {
      const float mo = __shfl_xor(m, mask);
      const float lo = __shfl_xor(l, mask);
      const float mn = fmaxf(m, mo);
      l = l * __expf(m - mn) + lo * __expf(mo - mn);
      m = mn;
    }
    if (b8 == 0) {
      const int p = p0 + 8 * it + c8;
      const size_t idx = ((size_t)(sg * 4 + w) * NH + h) * PP + p;
      m_part[idx] = m;
      l_part[idx] = l;
    }
  }
}

// ---------------- attnpv v4: pipelined compute phase + streaming fill phase ----
// grid: (P/64, 2, NH); block 256 = 4 waves, wave owns 16 p-rows.
__global__ __launch_bounds__(256, 2) void attnpv_kernel(
    const float* __restrict__ raw, const unsigned short* __restrict__ vT,
    const float* __restrict__ m_part, const float* __restrict__ l_part,
    float* __restrict__ attn, unsigned short* __restrict__ ctxp) {
  const int tid = threadIdx.x, lane = tid & 63, w = tid >> 6;
  const int pt = blockIdx.x, ss = blockIdx.y, h = blockIdx.z;
  const int p0 = pt * 64, wr = w * 16;
  const int g = lane >> 4, ln = lane & 15;
  const int myp = p0 + wr + ln;

  float m = -1e30f, l = 0.f;
#pragma unroll
  for (int sgw = 0; sgw < 16; ++sgw) {
    const size_t idx = ((size_t)sgw * NH + h) * PP + myp;
    const float mo = m_part[idx];
    const float lo = l_part[idx];
    const float mn = fmaxf(m, mo);
    l = l * __expf(m - mn) + lo * __expf(mo - mn);
    m = mn;
  }
  const float mm = m;
  const float il = 1.f / l;

  unsigned short* ctx = ctxp + (size_t)ss * PP * DDIM;
  const int base_s = ss * 1024;
  int ncomp = 0;
  if (p0 + 63 >= base_s) {
    ncomp = (p0 + 63 - base_s) / 128 + 1;
    ncomp = (ncomp > 8) ? 8 : ncomp;
  }

  f32x4 acc[4] = {};
  f32x4 rc[8];
  if (ncomp > 0) {
    const size_t rb0 = ((size_t)myp * NH + h) * SSEQ + base_s;
#pragma unroll
    for (int ks = 0; ks < 4; ++ks) {
      rc[2 * ks]     = *(const f32x4*)(raw + rb0 + ks * 32 + g * 8);
      rc[2 * ks + 1] = *(const f32x4*)(raw + rb0 + ks * 32 + g * 8 + 4);
    }
  }
  for (int st = 0; st < ncomp; ++st) {
    const int s0 = base_s + st * 128;
    const size_t rbase = ((size_t)myp * NH + h) * SSEQ + s0;
    // V fragments for this tile, issued first (L2-resident; lands under exp work)
    bf16x8 bv[4][4];
#pragma unroll
    for (int nj = 0; nj < 4; ++nj)
#pragma unroll
      for (int ks = 0; ks < 4; ++ks)
        bv[nj][ks] = *(const bf16x8*)(vT + (size_t)(h * DH + nj * 16 + ln) * SSEQ + s0 + ks * 32 + g * 8);
    // prefetch next tile's raw (hides HBM latency under this tile)
    f32x4 rn[8];
    if (st + 1 < ncomp) {
#pragma unroll
      for (int ks = 0; ks < 4; ++ks) {
        rn[2 * ks]     = *(const f32x4*)(raw + rbase + 128 + ks * 32 + g * 8);
        rn[2 * ks + 1] = *(const f32x4*)(raw + rbase + 128 + ks * 32 + g * 8 + 4);
      }
    }
    bf16x8 pa[4];
#pragma unroll
    for (int ks = 0; ks < 4; ++ks) {
      const int c0 = ks * 32 + g * 8;
      const int sb = s0 + c0;
      const f32x4 r0 = rc[2 * ks], r1 = rc[2 * ks + 1];
      f32x4 a0, a1;
      a0[0] = (sb + 0 <= myp) ? __expf(r0[0] - mm) * il : 0.f;
      a0[1] = (sb + 1 <= myp) ? __expf(r0[1] - mm) * il : 0.f;
      a0[2] = (sb + 2 <= myp) ? __expf(r0[2] - mm) * il : 0.f;
      a0[3] = (sb + 3 <= myp) ? __expf(r0[3] - mm) * il : 0.f;
      a1[0] = (sb + 4 <= myp) ? __expf(r1[0] - mm) * il : 0.f;
      a1[1] = (sb + 5 <= myp) ? __expf(r1[1] - mm) * il : 0.f;
      a1[2] = (sb + 6 <= myp) ? __expf(r1[2] - mm) * il : 0.f;
      a1[3] = (sb + 7 <= myp) ? __expf(r1[3] - mm) * il : 0.f;
      __builtin_nontemporal_store(a0, (f32x4*)(attn + rbase + c0));
      __builtin_nontemporal_store(a1, (f32x4*)(attn + rbase + c0 + 4));
      bf16x8 pk;
      pk[0] = f2bf(a0[0]); pk[1] = f2bf(a0[1]); pk[2] = f2bf(a0[2]); pk[3] = f2bf(a0[3]);
      pk[4] = f2bf(a1[0]); pk[5] = f2bf(a1[1]); pk[6] = f2bf(a1[2]); pk[7] = f2bf(a1[3]);
      pa[ks] = pk;
    }
#pragma unroll
    for (int nj = 0; nj < 4; ++nj)
#pragma unroll
      for (int ks = 0; ks < 4; ++ks)
        acc[nj] = __builtin_amdgcn_mfma_f32_16x16x32_bf16(pa[ks], bv[nj][ks], acc[nj], 0, 0, 0);
    if (st + 1 < ncomp) {
#pragma unroll
      for (int i = 0; i < 8; ++i) rc[i] = rn[i];
    }
  }
  // streaming zero-fill for fully-masked tiles
  const f32x4 z = {0.f, 0.f, 0.f, 0.f};
  for (int st = ncomp; st < 8; ++st) {
    const int s0 = base_s + st * 128;
#pragma unroll
    for (int i = 0; i < 8; ++i) {
      const int e = i * 1024 + lane * 16;
      const int row = e >> 9, colf = (e & 511) >> 2;
      __builtin_nontemporal_store(
          z, (f32x4*)(attn + ((size_t)(p0 + wr + row) * NH + h) * SSEQ + s0 + colf));
    }
  }
#pragma unroll
  for (int nj = 0; nj < 4; ++nj)
#pragma unroll
    for (int r = 0; r < 4; ++r) {
      const int p = p0 + wr + g * 4 + r;
      ctx[(size_t)p * DDIM + h * DH + nj * 16 + ln] = (unsigned short)f2bf(acc[nj][r]);
    }
}

extern "C" void kernel_launch(void* const* d_in, const int* in_sizes, int n_in,
                              void* d_out, int out_size, void* d_ws, size_t ws_size,
                              hipStream_t stream) {
  (void)in_sizes; (void)n_in; (void)out_size; (void)ws_size;
  const float* Q    = (const float*)d_in[0];
  const float* K    = (const float*)d_in[1];
  const float* V    = (const float*)d_in[2];
  const float* prev = (const float*)d_in[3];
  const float* Wq   = (const float*)d_in[4];
  const float* bq   = (const float*)d_in[5];
  const float* Wk   = (const float*)d_in[6];
  const float* bk   = (const float*)d_in[7];
  const float* Wv   = (const float*)d_in[8];
  const float* bv   = (const float*)d_in[9];
  const float* Wo   = (const float*)d_in[10];
  const float* bo   = (const float*)d_in[11];
  const float* ch_gate = (const float*)d_in[12];

  float* out  = (float*)d_out;                       // (2048,1024)
  float* attn = out + (size_t)PP * DDIM;             // (2048,16,2048)
  float* raw  = attn + (size_t)PP * NH * SSEQ;       // (2048,16,2048)

  unsigned short* qb    = (unsigned short*)d_ws;
  unsigned short* kb    = qb + (size_t)PP * DDIM;
  unsigned short* vb    = kb + (size_t)PP * DDIM;
  unsigned short* vT    = vb + (size_t)PP * DDIM;
  unsigned short* ctxp  = vT + (size_t)DDIM * SSEQ;
  float* m_part = (float*)(ctxp + (size_t)2 * PP * DDIM);
  float* l_part = m_part + (size_t)16 * NH * PP;

  dim3 blk(256);
  qkv_proj<<<dim3(DDIM / 128, PP / 64, 3), blk, 0, stream>>>(
      Q, K, V, Wq, Wk, Wv, bq, bk, bv, qb, kb, vb);
  transpose_v<<<dim3(SSEQ / 64, DDIM / 64), blk, 0, stream>>>(vb, vT);
  scores_kernel<<<dim3(PP / 64, 4, NH), blk, 0, stream>>>(
      qb, kb, prev, ch_gate, raw, m_part, l_part);
  attnpv_kernel<<<dim3(PP / 64, 2, NH), blk, 0, stream>>>(
      raw, vT, m_part, l_part, attn, ctxp);
  out_proj<<<dim3(DDIM / 128, PP / 64), blk, 0, stream>>>(
      ctxp, ctxp + (size_t)PP * DDIM, Wo, bo, out);
}

// Round 7
// 395.979 us; speedup vs baseline: 3.2753x; 1.1634x over previous
//
#include <hip/hip_runtime.h>

#define PP 2048     // P (pred rows)
#define SSEQ 2048   // S (key rows)
#define DDIM 1024   // D
#define NH 16       // heads
#define DH 64       // head dim

typedef __attribute__((ext_vector_type(4))) float f32x4;
typedef __attribute__((ext_vector_type(8))) short bf16x8;
typedef __attribute__((ext_vector_type(4))) short bf16x4;

__device__ __forceinline__ short f2bf(float f) {
  unsigned u = __builtin_bit_cast(unsigned, f);
  u += 0x7FFFu + ((u >> 16) & 1u);   // RNE
  return (short)(u >> 16);
}
__device__ __forceinline__ float bf2f(unsigned short u) {
  return __builtin_bit_cast(float, ((unsigned)u) << 16);
}
__device__ __forceinline__ void gld_lds16(const void* g, void* l) {
  __builtin_amdgcn_global_load_lds(
      (const __attribute__((address_space(1))) void*)g,
      (__attribute__((address_space(3))) void*)l, 16, 0, 0);
}

// ---------------- bf16 conversion: 7 buffers in one launch ----------------
__global__ __launch_bounds__(256) void cvt7(
    const float* __restrict__ s0, const float* __restrict__ s1, const float* __restrict__ s2,
    const float* __restrict__ s3, const float* __restrict__ s4, const float* __restrict__ s5,
    const float* __restrict__ s6,
    unsigned short* __restrict__ d0, unsigned short* __restrict__ d1, unsigned short* __restrict__ d2,
    unsigned short* __restrict__ d3, unsigned short* __restrict__ d4, unsigned short* __restrict__ d5,
    unsigned short* __restrict__ d6) {
  const int z = blockIdx.y;
  const float* s = (z == 0) ? s0 : (z == 1) ? s1 : (z == 2) ? s2 : (z == 3) ? s3
                 : (z == 4) ? s4 : (z == 5) ? s5 : s6;
  unsigned short* d = (z == 0) ? d0 : (z == 1) ? d1 : (z == 2) ? d2 : (z == 3) ? d3
                    : (z == 4) ? d4 : (z == 5) ? d5 : d6;
  const size_t n = (z < 3) ? (size_t)PP * DDIM : (size_t)DDIM * DDIM;
  const size_t i = ((size_t)blockIdx.x * 256 + threadIdx.x) * 8;
  if (i >= n) return;
  const float4 x0 = *(const float4*)(s + i);
  const float4 x1 = *(const float4*)(s + i + 4);
  bf16x8 o;
  o[0] = f2bf(x0.x); o[1] = f2bf(x0.y); o[2] = f2bf(x0.z); o[3] = f2bf(x0.w);
  o[4] = f2bf(x1.x); o[5] = f2bf(x1.y); o[6] = f2bf(x1.z); o[7] = f2bf(x1.w);
  *(bf16x8*)(d + i) = o;
}

// ---------------- ctx partial sum: ctxb = ctxp0 + ctxp1 (bf16) ----------------
__global__ __launch_bounds__(256) void sumctx(
    const unsigned short* __restrict__ a, const unsigned short* __restrict__ b,
    unsigned short* __restrict__ o) {
  const size_t i = ((size_t)blockIdx.x * 256 + threadIdx.x) * 8;
  const bf16x8 av = *(const bf16x8*)(a + i);
  const bf16x8 bv = *(const bf16x8*)(b + i);
  bf16x8 ov;
#pragma unroll
  for (int u = 0; u < 8; ++u)
    ov[u] = f2bf(bf2f((unsigned short)av[u]) + bf2f((unsigned short)bv[u]));
  *(bf16x8*)(o + i) = ov;
}

// ---------------- GEMM (m97 structure): Y[2048][1024] = A @ B^T + bias ------
// 128x128 tile, BK=32, 4 waves (2x2), wave = 64x64 via 4x4 16x16x32 MFMA.
// A,B bf16 staged via global_load_lds width-16 (no VALU staging).
template<int YF32>
__device__ __forceinline__ void gemm128_body(
    const unsigned short* __restrict__ A, const unsigned short* __restrict__ B,
    const float* __restrict__ bias, void* __restrict__ Yv) {
  __shared__ unsigned short As[4096];   // 128x32 linear (gload_lds: no pad)
  __shared__ unsigned short Bs[4096];
  const int tid = threadIdx.x, lane = tid & 63, w = tid >> 6;
  const int m0 = blockIdx.y * 128, n0 = blockIdx.x * 128;
  const int g = lane >> 4, ln = lane & 15;
  const int wm = (w >> 1) * 64, wn = (w & 1) * 64;
  const int sr = tid >> 2, sc = (tid & 3) * 8;   // staging: row tid/4, col (tid%4)*8
  unsigned short* asd0 = As + w * 512;           // wave-uniform LDS dest bases
  unsigned short* asd1 = As + 2048 + w * 512;
  unsigned short* bsd0 = Bs + w * 512;
  unsigned short* bsd1 = Bs + 2048 + w * 512;
  f32x4 acc[4][4] = {};
  for (int k0 = 0; k0 < DDIM; k0 += 32) {
    __syncthreads();
    gld_lds16(A + (size_t)(m0 + sr) * DDIM + k0 + sc, asd0);
    gld_lds16(A + (size_t)(m0 + 64 + sr) * DDIM + k0 + sc, asd1);
    gld_lds16(B + (size_t)(n0 + sr) * DDIM + k0 + sc, bsd0);
    gld_lds16(B + (size_t)(n0 + 64 + sr) * DDIM + k0 + sc, bsd1);
    __syncthreads();
    bf16x8 a[4], b[4];
#pragma unroll
    for (int mi = 0; mi < 4; ++mi) a[mi] = *(const bf16x8*)&As[(wm + mi * 16 + ln) * 32 + g * 8];
#pragma unroll
    for (int ni = 0; ni < 4; ++ni) b[ni] = *(const bf16x8*)&Bs[(wn + ni * 16 + ln) * 32 + g * 8];
#pragma unroll
    for (int mi = 0; mi < 4; ++mi)
#pragma unroll
      for (int ni = 0; ni < 4; ++ni)
        acc[mi][ni] = __builtin_amdgcn_mfma_f32_16x16x32_bf16(a[mi], b[ni], acc[mi][ni], 0, 0, 0);
  }
  // C/D layout: col = lane&15, row = (lane>>4)*4 + r
#pragma unroll
  for (int mi = 0; mi < 4; ++mi)
#pragma unroll
    for (int ni = 0; ni < 4; ++ni) {
      const int n = n0 + wn + ni * 16 + ln;
      const float bs = bias[n];
#pragma unroll
      for (int r = 0; r < 4; ++r) {
        const int m = m0 + wm + mi * 16 + g * 4 + r;
        const float v = acc[mi][ni][r] + bs;
        if (YF32) ((float*)Yv)[(size_t)m * DDIM + n] = v;
        else ((unsigned short*)Yv)[(size_t)m * DDIM + n] = (unsigned short)f2bf(v);
      }
    }
}

__global__ __launch_bounds__(256, 2) void qkv_gemm(
    const unsigned short* __restrict__ Qb, const unsigned short* __restrict__ Kb,
    const unsigned short* __restrict__ Vb,
    const unsigned short* __restrict__ Wq, const unsigned short* __restrict__ Wk,
    const unsigned short* __restrict__ Wv,
    const float* __restrict__ bq, const float* __restrict__ bk, const float* __restrict__ bv,
    unsigned short* __restrict__ qo, unsigned short* __restrict__ ko,
    unsigned short* __restrict__ vo) {
  const int z = blockIdx.z;
  gemm128_body<0>((z == 0) ? Qb : (z == 1) ? Kb : Vb,
                  (z == 0) ? Wq : (z == 1) ? Wk : Wv,
                  (z == 0) ? bq : (z == 1) ? bk : bv,
                  (z == 0) ? qo : (z == 1) ? ko : vo);
}

__global__ __launch_bounds__(256, 2) void out_gemm(
    const unsigned short* __restrict__ A, const unsigned short* __restrict__ B,
    const float* __restrict__ bias, float* __restrict__ Y) {
  gemm128_body<1>(A, B, bias, Y);
}

// ---------------- V transpose: vT[d][s] = vb[s][d] ----------------
__global__ __launch_bounds__(256) void transpose_v(
    const unsigned short* __restrict__ vb, unsigned short* __restrict__ vT) {
  __shared__ unsigned short t[64][72];
  const int tid = threadIdx.x;
  const int sb = blockIdx.x * 64, db = blockIdx.y * 64;
#pragma unroll
  for (int pass = 0; pass < 2; ++pass) {
    const int e = pass * 2048 + tid * 8;
    const int r = e >> 6, c = e & 63;
    *(bf16x8*)&t[r][c] = *(const bf16x8*)(vb + (size_t)(sb + r) * DDIM + db + c);
  }
  __syncthreads();
#pragma unroll
  for (int pass = 0; pass < 2; ++pass) {
    const int e = pass * 2048 + tid * 8;
    const int r = e >> 6, c = e & 63;   // r: d row, c: s col
    bf16x8 ov;
#pragma unroll
    for (int u = 0; u < 8; ++u) ov[u] = (short)t[c + u][r];
    *(bf16x8*)(vT + (size_t)(db + r) * SSEQ + sb + c) = ov;
  }
}

// ---------------- scores v4 (identical to R6) ----------------
__global__ __launch_bounds__(256, 3) void scores_kernel(
    const unsigned short* __restrict__ qb, const unsigned short* __restrict__ kb,
    const float* __restrict__ prev, const float* __restrict__ ch_gate,
    float* __restrict__ raw, float* __restrict__ m_part, float* __restrict__ l_part) {
  __shared__ float Rs[4][32][68];   // [wave][col-in-strip][row(+pad)]
  const int tid = threadIdx.x, lane = tid & 63, w = tid >> 6;
  const int pt = blockIdx.x, sg = blockIdx.y, h = blockIdx.z;
  const int p0 = pt * 64;
  const int g = lane >> 4, ln = lane & 15;
  const int b8 = lane & 7, c8 = lane >> 3;

  bf16x8 aq[4][2];
#pragma unroll
  for (int mi = 0; mi < 4; ++mi)
#pragma unroll
    for (int ks = 0; ks < 2; ++ks)
      aq[mi][ks] = *(const bf16x8*)(qb + (size_t)(p0 + mi * 16 + ln) * DDIM + h * DH + ks * 32 + g * 8);

  const int pc = p0 >> 8;
  float mrun[8], lrun[8];
#pragma unroll
  for (int i = 0; i < 8; ++i) { mrun[i] = -1e30f; lrun[i] = 0.f; }

  f32x4 pv[8];
  {
    const int sw0 = sg * 512 + w * 32;
#pragma unroll
    for (int it = 0; it < 8; ++it)
      pv[it] = __builtin_nontemporal_load(
          (const f32x4*)(prev + ((size_t)(p0 + 8 * it + c8) * NH + h) * SSEQ + sw0 + b8 * 4));
  }

#pragma unroll
  for (int t = 0; t < 4; ++t) {
    const int s0 = sg * 512 + t * 128;
    const int sw = s0 + w * 32;
    const float gate = (ch_gate[pc * 8 + (s0 >> 8)] >= 0.f) ? 1.f : 0.f;
    bf16x8 bk_[2][2];
#pragma unroll
    for (int nj = 0; nj < 2; ++nj)
#pragma unroll
      for (int ks = 0; ks < 2; ++ks)
        bk_[nj][ks] = *(const bf16x8*)(kb + (size_t)(sw + nj * 16 + ln) * DDIM + h * DH + ks * 32 + g * 8);
    f32x4 pvn[8];
    if (t < 3) {
      const int swn = sw + 128;
#pragma unroll
      for (int it = 0; it < 8; ++it)
        pvn[it] = __builtin_nontemporal_load(
            (const f32x4*)(prev + ((size_t)(p0 + 8 * it + c8) * NH + h) * SSEQ + swn + b8 * 4));
    }
    f32x4 acc[4][2] = {};
#pragma unroll
    for (int ks = 0; ks < 2; ++ks)
#pragma unroll
      for (int mi = 0; mi < 4; ++mi)
#pragma unroll
        for (int nj = 0; nj < 2; ++nj)
          acc[mi][nj] = __builtin_amdgcn_mfma_f32_16x16x32_bf16(aq[mi][ks], bk_[nj][ks], acc[mi][nj], 0, 0, 0);
#pragma unroll
    for (int mi = 0; mi < 4; ++mi)
#pragma unroll
      for (int nj = 0; nj < 2; ++nj)
        *(f32x4*)&Rs[w][nj * 16 + ln][mi * 16 + g * 4] = acc[mi][nj];
#pragma unroll
    for (int it = 0; it < 8; ++it) {
      const int row = 8 * it + c8;
      const int p = p0 + row;
      const int sq = sw + b8 * 4;
      f32x4 v;
      v[0] = fmaf(Rs[w][b8 * 4 + 0][row], 0.125f, pv[it][0]) * gate;
      v[1] = fmaf(Rs[w][b8 * 4 + 1][row], 0.125f, pv[it][1]) * gate;
      v[2] = fmaf(Rs[w][b8 * 4 + 2][row], 0.125f, pv[it][2]) * gate;
      v[3] = fmaf(Rs[w][b8 * 4 + 3][row], 0.125f, pv[it][3]) * gate;
      __builtin_nontemporal_store(v, (f32x4*)(raw + ((size_t)p * NH + h) * SSEQ + sq));
      if (sq <= p) {
        const float v0 = v[0];
        const float v1 = (sq + 1 <= p) ? v[1] : -1e30f;
        const float v2 = (sq + 2 <= p) ? v[2] : -1e30f;
        const float v3 = (sq + 3 <= p) ? v[3] : -1e30f;
        const float qm = fmaxf(fmaxf(v0, v1), fmaxf(v2, v3));
        const float mn = fmaxf(mrun[it], qm);
        lrun[it] = lrun[it] * __expf(mrun[it] - mn)
                 + __expf(v0 - mn) + __expf(v1 - mn) + __expf(v2 - mn) + __expf(v3 - mn);
        mrun[it] = mn;
      }
    }
    if (t < 3) {
#pragma unroll
      for (int it = 0; it < 8; ++it) pv[it] = pvn[it];
    }
  }
#pragma unroll
  for (int it = 0; it < 8; ++it) {
    float m = mrun[it], l = lrun[it];
#pragma unroll
    for (int mask = 1; mask < 8; mask <<= 1) {
      const float mo = __shfl_xor(m, mask);
      const float lo = __shfl_xor(l, mask);
      const float mn = fmaxf(m, mo);
      l = l * __expf(m - mn) + lo * __expf(mo - mn);
      m = mn;
    }
    if (b8 == 0) {
      const int p = p0 + 8 * it + c8;
      const size_t idx = ((size_t)(sg * 4 + w) * NH + h) * PP + p;
      m_part[idx] = m;
      l_part[idx] = l;
    }
  }
}

// ---------------- attnpv v4 (identical to R6) ----------------
__global__ __launch_bounds__(256, 2) void attnpv_kernel(
    const float* __restrict__ raw, const unsigned short* __restrict__ vT,
    const float* __restrict__ m_part, const float* __restrict__ l_part,
    float* __restrict__ attn, unsigned short* __restrict__ ctxp) {
  const int tid = threadIdx.x, lane = tid & 63, w = tid >> 6;
  const int pt = blockIdx.x, ss = blockIdx.y, h = blockIdx.z;
  const int p0 = pt * 64, wr = w * 16;
  const int g = lane >> 4, ln = lane & 15;
  const int myp = p0 + wr + ln;

  float m = -1e30f, l = 0.f;
#pragma unroll
  for (int sgw = 0; sgw < 16; ++sgw) {
    const size_t idx = ((size_t)sgw * NH + h) * PP + myp;
    const float mo = m_part[idx];
    const float lo = l_part[idx];
    const float mn = fmaxf(m, mo);
    l = l * __expf(m - mn) + lo * __expf(mo - mn);
    m = mn;
  }
  const float mm = m;
  const float il = 1.f / l;

  unsigned short* ctx = ctxp + (size_t)ss * PP * DDIM;
  const int base_s = ss * 1024;
  int ncomp = 0;
  if (p0 + 63 >= base_s) {
    ncomp = (p0 + 63 - base_s) / 128 + 1;
    ncomp = (ncomp > 8) ? 8 : ncomp;
  }

  f32x4 acc[4] = {};
  f32x4 rc[8];
  if (ncomp > 0) {
    const size_t rb0 = ((size_t)myp * NH + h) * SSEQ + base_s;
#pragma unroll
    for (int ks = 0; ks < 4; ++ks) {
      rc[2 * ks]     = *(const f32x4*)(raw + rb0 + ks * 32 + g * 8);
      rc[2 * ks + 1] = *(const f32x4*)(raw + rb0 + ks * 32 + g * 8 + 4);
    }
  }
  for (int st = 0; st < ncomp; ++st) {
    const int s0 = base_s + st * 128;
    const size_t rbase = ((size_t)myp * NH + h) * SSEQ + s0;
    bf16x8 bv[4][4];
#pragma unroll
    for (int nj = 0; nj < 4; ++nj)
#pragma unroll
      for (int ks = 0; ks < 4; ++ks)
        bv[nj][ks] = *(const bf16x8*)(vT + (size_t)(h * DH + nj * 16 + ln) * SSEQ + s0 + ks * 32 + g * 8);
    f32x4 rn[8];
    if (st + 1 < ncomp) {
#pragma unroll
      for (int ks = 0; ks < 4; ++ks) {
        rn[2 * ks]     = *(const f32x4*)(raw + rbase + 128 + ks * 32 + g * 8);
        rn[2 * ks + 1] = *(const f32x4*)(raw + rbase + 128 + ks * 32 + g * 8 + 4);
      }
    }
    bf16x8 pa[4];
#pragma unroll
    for (int ks = 0; ks < 4; ++ks) {
      const int c0 = ks * 32 + g * 8;
      const int sb = s0 + c0;
      const f32x4 r0 = rc[2 * ks], r1 = rc[2 * ks + 1];
      f32x4 a0, a1;
      a0[0] = (sb + 0 <= myp) ? __expf(r0[0] - mm) * il : 0.f;
      a0[1] = (sb + 1 <= myp) ? __expf(r0[1] - mm) * il : 0.f;
      a0[2] = (sb + 2 <= myp) ? __expf(r0[2] - mm) * il : 0.f;
      a0[3] = (sb + 3 <= myp) ? __expf(r0[3] - mm) * il : 0.f;
      a1[0] = (sb + 4 <= myp) ? __expf(r1[0] - mm) * il : 0.f;
      a1[1] = (sb + 5 <= myp) ? __expf(r1[1] - mm) * il : 0.f;
      a1[2] = (sb + 6 <= myp) ? __expf(r1[2] - mm) * il : 0.f;
      a1[3] = (sb + 7 <= myp) ? __expf(r1[3] - mm) * il : 0.f;
      __builtin_nontemporal_store(a0, (f32x4*)(attn + rbase + c0));
      __builtin_nontemporal_store(a1, (f32x4*)(attn + rbase + c0 + 4));
      bf16x8 pk;
      pk[0] = f2bf(a0[0]); pk[1] = f2bf(a0[1]); pk[2] = f2bf(a0[2]); pk[3] = f2bf(a0[3]);
      pk[4] = f2bf(a1[0]); pk[5] = f2bf(a1[1]); pk[6] = f2bf(a1[2]); pk[7] = f2bf(a1[3]);
      pa[ks] = pk;
    }
#pragma unroll
    for (int nj = 0; nj < 4; ++nj)
#pragma unroll
      for (int ks = 0; ks < 4; ++ks)
        acc[nj] = __builtin_amdgcn_mfma_f32_16x16x32_bf16(pa[ks], bv[nj][ks], acc[nj], 0, 0, 0);
    if (st + 1 < ncomp) {
#pragma unroll
      for (int i = 0; i < 8; ++i) rc[i] = rn[i];
    }
  }
  const f32x4 z = {0.f, 0.f, 0.f, 0.f};
  for (int st = ncomp; st < 8; ++st) {
    const int s0 = base_s + st * 128;
#pragma unroll
    for (int i = 0; i < 8; ++i) {
      const int e = i * 1024 + lane * 16;
      const int row = e >> 9, colf = (e & 511) >> 2;
      __builtin_nontemporal_store(
          z, (f32x4*)(attn + ((size_t)(p0 + wr + row) * NH + h) * SSEQ + s0 + colf));
    }
  }
#pragma unroll
  for (int nj = 0; nj < 4; ++nj)
#pragma unroll
    for (int r = 0; r < 4; ++r) {
      const int p = p0 + wr + g * 4 + r;
      ctx[(size_t)p * DDIM + h * DH + nj * 16 + ln] = (unsigned short)f2bf(acc[nj][r]);
    }
}

extern "C" void kernel_launch(void* const* d_in, const int* in_sizes, int n_in,
                              void* d_out, int out_size, void* d_ws, size_t ws_size,
                              hipStream_t stream) {
  (void)in_sizes; (void)n_in; (void)out_size; (void)ws_size;
  const float* Q    = (const float*)d_in[0];
  const float* K    = (const float*)d_in[1];
  const float* V    = (const float*)d_in[2];
  const float* prev = (const float*)d_in[3];
  const float* Wq   = (const float*)d_in[4];
  const float* bq   = (const float*)d_in[5];
  const float* Wk   = (const float*)d_in[6];
  const float* bk   = (const float*)d_in[7];
  const float* Wv   = (const float*)d_in[8];
  const float* bv   = (const float*)d_in[9];
  const float* Wo   = (const float*)d_in[10];
  const float* bo   = (const float*)d_in[11];
  const float* ch_gate = (const float*)d_in[12];

  float* out  = (float*)d_out;                       // (2048,1024)
  float* attn = out + (size_t)PP * DDIM;             // (2048,16,2048)
  float* raw  = attn + (size_t)PP * NH * SSEQ;       // (2048,16,2048)

  // ws layout (40MB, lifetime-overlapped):
  unsigned short* ws16  = (unsigned short*)d_ws;
  unsigned short* qb    = ws16;                      // 2M elems
  unsigned short* kb    = qb + 2097152;
  unsigned short* vb    = kb + 2097152;
  unsigned short* vT    = vb + 2097152;
  unsigned short* ctxp0 = vT + 2097152;              // phase 1: Qbf
  unsigned short* ctxp1 = ctxp0 + 2097152;           // phase 1: Kbf
  unsigned short* ctxb  = ctxp1 + 2097152;           // phase 1: Vbf
  float* m_part = (float*)(ctxb + 2097152);          // (16,16,2048)
  float* l_part = m_part + 524288;
  unsigned short* wqb = (unsigned short*)(l_part + 524288);  // 1M elems each
  unsigned short* wkb = wqb + 1048576;
  unsigned short* wvb = wkb + 1048576;
  unsigned short* wob = wvb + 1048576;

  unsigned short* Qbf = ctxp0;   // aliases (dead before ctx writes)
  unsigned short* Kbf = ctxp1;
  unsigned short* Vbf = ctxb;

  dim3 blk(256);
  cvt7<<<dim3(1024, 7), blk, 0, stream>>>(
      Q, K, V, Wq, Wk, Wv, Wo, Qbf, Kbf, Vbf, wqb, wkb, wvb, wob);
  qkv_gemm<<<dim3(DDIM / 128, PP / 128, 3), blk, 0, stream>>>(
      Qbf, Kbf, Vbf, wqb, wkb, wvb, bq, bk, bv, qb, kb, vb);
  transpose_v<<<dim3(SSEQ / 64, DDIM / 64), blk, 0, stream>>>(vb, vT);
  scores_kernel<<<dim3(PP / 64, 4, NH), blk, 0, stream>>>(
      qb, kb, prev, ch_gate, raw, m_part, l_part);
  attnpv_kernel<<<dim3(PP / 64, 2, NH), blk, 0, stream>>>(
      raw, vT, m_part, l_part, attn, ctxp0);
  sumctx<<<dim3(1024), blk, 0, stream>>>(ctxp0, ctxp1, ctxb);
  out_gemm<<<dim3(DDIM / 128, PP / 128), blk, 0, stream>>>(ctxb, wob, bo, out);
}